// Round 1
// baseline (188.840 us; speedup 1.0000x reference)
//
#include <hip/hip_runtime.h>

typedef __attribute__((ext_vector_type(8))) short bf16x8;
typedef __attribute__((ext_vector_type(4))) float f32x4;
typedef __attribute__((ext_vector_type(8))) unsigned short u16x8;

#define NT 26
#define BROWS 64
#define NKS 16            // k-steps of 32 over the 512-wide (padded) cat block
#define LDSTR 520         // bf16 elems per LDS row (508 cat + 4 zero + 8 pad); 1040B stride
#define HSTR 33           // fp32 h row stride (dwords)
#define Z1STR 68          // fp32 z1 row stride (dwords)

__constant__ int c_OFFS[NT] = {
    0,1000001,1500002,1600003,1650004,1660005,1670006,1675007,1680008,1681009,
    1682010,1682511,1683012,1683113,1683214,1683265,1683316,1683337,1683358,
    1683369,1683380,1683386,1683392,1683396,1683400,1683403};
__constant__ int c_DIMS[NT] = {
    32,32,32,32,32,32,32,32,32,32,32,32,21,21,14,14,9,9,6,6,4,4,4,4,4,4};
__constant__ int c_COLF[NT] = {
    0,32,64,96,128,160,192,224,256,288,320,352,384,405,426,440,454,463,
    472,478,484,488,492,496,500,504};

__device__ __forceinline__ unsigned short f2bf(float f) {
  unsigned int u = __builtin_bit_cast(unsigned int, f);
  u += 0x7fffu + ((u >> 16) & 1u);       // RNE
  return (unsigned short)(u >> 16);
}

__device__ __forceinline__ float silu_f(float x) {
  return x / (1.0f + __expf(-x));
}

extern "C" __global__ void __launch_bounds__(256, 2)
tab_fused(const float* __restrict__ xc,   // [B,64]
          const int* __restrict__ xcat,   // [B,26]
          const float* __restrict__ emb,  // [TOTAL_ROWS,32]
          const float* __restrict__ Wc,   // [64,32]
          const float* __restrict__ bc,   // [32]
          const float* __restrict__ lng,  // [32]
          const float* __restrict__ lnb,  // [32]
          const float* __restrict__ W1,   // [540,64]
          const float* __restrict__ b1,   // [64]
          const float* __restrict__ W2,   // [64,32]
          const float* __restrict__ b2,   // [32]
          float* __restrict__ out) {      // [B,32]
  // cat tile (bf16) lives here during phases 1-2, z1 (fp32) aliases it after.
  __shared__ __attribute__((aligned(16))) float smem[(BROWS * LDSTR) / 2]; // 66,560 B
  __shared__ __attribute__((aligned(16))) float hf[BROWS * HSTR];          //  8,448 B
  unsigned short* fused = (unsigned short*)smem;
  float* z1 = smem;

  const int t  = threadIdx.x;
  const int w  = t >> 6;          // wave id 0..3
  const int l  = t & 63;          // lane
  const int R0 = blockIdx.x * BROWS;

  // ---------------- phase 0: stage W1 into registers ----------------
  const int bn = (w << 4) + (l & 15);   // z1 column owned by this lane (wave = n-tile)
  const int kg = (l >> 4) << 3;         // k sub-offset 0/8/16/24 within a 32-k step
  float w1h[32];                        // W1 rows 0..31 (fp32, for the h part)
  #pragma unroll
  for (int j = 0; j < 32; ++j) w1h[j] = W1[j * 64 + bn];
  bf16x8 bfw[NKS];                      // W1 rows 32..539 as bf16 B-fragments
  #pragma unroll
  for (int ks = 0; ks < NKS; ++ks) {
    #pragma unroll
    for (int j = 0; j < 8; ++j) {
      const int k = 32 + (ks << 5) + kg + j;   // global W1 row
      const float v = (k < 540) ? W1[k * 64 + bn] : 0.0f;
      bfw[ks][j] = (short)f2bf(v);
    }
  }

  // ---------------- phase 1: cont MLP (wave 0) | embedding gather (waves 1-3) ----
  if (w == 0) {
    // one lane per batch row: Linear(64,32) + LayerNorm + SiLU, all fp32
    const float* xr = xc + (size_t)(R0 + l) * 64;
    float h[32];
    #pragma unroll
    for (int j = 0; j < 32; ++j) h[j] = bc[j];
    #pragma unroll 4
    for (int k4 = 0; k4 < 16; ++k4) {
      const float4 x4 = ((const float4*)xr)[k4];
      const float* w0 = Wc + (k4 * 4) * 32;
      #pragma unroll
      for (int j = 0; j < 32; ++j) {
        h[j] = __fmaf_rn(x4.x, w0[j],      h[j]);
        h[j] = __fmaf_rn(x4.y, w0[32 + j], h[j]);
        h[j] = __fmaf_rn(x4.z, w0[64 + j], h[j]);
        h[j] = __fmaf_rn(x4.w, w0[96 + j], h[j]);
      }
    }
    float mu = 0.f;
    #pragma unroll
    for (int j = 0; j < 32; ++j) mu += h[j];
    mu *= 0.03125f;
    float var = 0.f;
    #pragma unroll
    for (int j = 0; j < 32; ++j) { const float d = h[j] - mu; var += d * d; }
    var *= 0.03125f;
    const float rs = rsqrtf(var + 1e-5f);
    float* hrow = &hf[l * HSTR];
    #pragma unroll
    for (int j = 0; j < 32; ++j) {
      const float v = (h[j] - mu) * rs * lng[j] + lnb[j];
      hrow[j] = silu_f(v);
    }
    // zero the 4 pad cols (508..511) of this row's cat tile
    unsigned short* pz = &fused[l * LDSTR + 508];
    pz[0] = 0; pz[1] = 0; pz[2] = 0; pz[3] = 0;
  } else {
    // 192 threads cover 64 rows x 26 tables = 1664 gathers
    const int g = t - 64;
    for (int p = g; p < BROWS * NT; p += 192) {
      const int r = p / NT;
      const int i = p - r * NT;
      const int idx = xcat[(size_t)(R0 + r) * NT + i];
      const float* src = emb + (size_t)(c_OFFS[i] + idx) * 32;
      unsigned short* dst = &fused[r * LDSTR + c_COLF[i]];
      const int d = c_DIMS[i];
      if (d == 32) {
        const float4* s4 = (const float4*)src;
        const float4 f0 = s4[0], f1 = s4[1], f2 = s4[2], f3 = s4[3];
        const float4 f4 = s4[4], f5 = s4[5], f6 = s4[6], f7 = s4[7];
        u16x8 o0, o1, o2, o3;
        o0[0]=f2bf(f0.x); o0[1]=f2bf(f0.y); o0[2]=f2bf(f0.z); o0[3]=f2bf(f0.w);
        o0[4]=f2bf(f1.x); o0[5]=f2bf(f1.y); o0[6]=f2bf(f1.z); o0[7]=f2bf(f1.w);
        o1[0]=f2bf(f2.x); o1[1]=f2bf(f2.y); o1[2]=f2bf(f2.z); o1[3]=f2bf(f2.w);
        o1[4]=f2bf(f3.x); o1[5]=f2bf(f3.y); o1[6]=f2bf(f3.z); o1[7]=f2bf(f3.w);
        o2[0]=f2bf(f4.x); o2[1]=f2bf(f4.y); o2[2]=f2bf(f4.z); o2[3]=f2bf(f4.w);
        o2[4]=f2bf(f5.x); o2[5]=f2bf(f5.y); o2[6]=f2bf(f5.z); o2[7]=f2bf(f5.w);
        o3[0]=f2bf(f6.x); o3[1]=f2bf(f6.y); o3[2]=f2bf(f6.z); o3[3]=f2bf(f6.w);
        o3[4]=f2bf(f7.x); o3[5]=f2bf(f7.y); o3[6]=f2bf(f7.z); o3[7]=f2bf(f7.w);
        u16x8* d8 = (u16x8*)dst;           // 16B-aligned: coloff*2 % 16 == 0, 1040*r % 16 == 0
        d8[0] = o0; d8[1] = o1; d8[2] = o2; d8[3] = o3;
      } else {
        for (int c = 0; c < d; ++c) dst[c] = f2bf(src[c]);
      }
    }
  }
  __syncthreads();

  // ---------------- phase 2: MFMA over the 512-wide cat block ----------------
  f32x4 acc[4];
  #pragma unroll
  for (int mt = 0; mt < 4; ++mt) acc[mt] = (f32x4){0.f, 0.f, 0.f, 0.f};
  #pragma unroll
  for (int mt = 0; mt < 4; ++mt) {
    const unsigned short* arow = &fused[((mt << 4) + (l & 15)) * LDSTR + kg];
    #pragma unroll
    for (int ks = 0; ks < NKS; ++ks) {
      const bf16x8 a = *(const bf16x8*)(arow + (ks << 5));
      acc[mt] = __builtin_amdgcn_mfma_f32_16x16x32_bf16(a, bfw[ks], acc[mt], 0, 0, 0);
    }
  }
  __syncthreads();   // everyone done reading the cat tile; safe to alias z1

  // ---------------- phase 2.5: z1 = silu(cat@W1[32:] + h@W1[:32] + b1) --------
  const float b1v = b1[bn];
  const int rb = (l >> 4) << 2;
  #pragma unroll
  for (int mt = 0; mt < 4; ++mt) {
    #pragma unroll
    for (int v = 0; v < 4; ++v) {
      const int row = (mt << 4) + rb + v;          // C/D layout: row=(l>>4)*4+reg
      const float* hrow = &hf[row * HSTR];
      float s = acc[mt][v] + b1v;
      #pragma unroll
      for (int j = 0; j < 32; ++j) s = __fmaf_rn(hrow[j], w1h[j], s);
      z1[row * Z1STR + bn] = silu_f(s);
    }
  }
  __syncthreads();

  // ---------------- phase 3: out = silu(z1 @ W2 + b2) ------------------------
  {
    const int r  = t >> 2;            // 4 threads per row
    const int j0 = (t & 3) << 3;      // 8 output cols each
    float a2[8];
    #pragma unroll
    for (int u = 0; u < 8; ++u) a2[u] = b2[j0 + u];
    const float* zr = &z1[r * Z1STR];
    #pragma unroll 8
    for (int k = 0; k < 64; ++k) {
      const float zv = zr[k];
      const float* w2r = W2 + k * 32 + j0;
      #pragma unroll
      for (int u = 0; u < 8; ++u) a2[u] = __fmaf_rn(zv, w2r[u], a2[u]);
    }
    float4 o0, o1;
    o0.x = silu_f(a2[0]); o0.y = silu_f(a2[1]); o0.z = silu_f(a2[2]); o0.w = silu_f(a2[3]);
    o1.x = silu_f(a2[4]); o1.y = silu_f(a2[5]); o1.z = silu_f(a2[6]); o1.w = silu_f(a2[7]);
    float* orow = out + (size_t)(R0 + r) * 32 + j0;
    ((float4*)orow)[0] = o0;
    ((float4*)orow)[1] = o1;
  }
}

extern "C" void kernel_launch(void* const* d_in, const int* in_sizes, int n_in,
                              void* d_out, int out_size, void* d_ws, size_t ws_size,
                              hipStream_t stream) {
  const float* xc   = (const float*)d_in[0];
  const int*   xcat = (const int*)  d_in[1];
  const float* emb  = (const float*)d_in[2];
  const float* Wc   = (const float*)d_in[3];
  const float* bc   = (const float*)d_in[4];
  const float* lng  = (const float*)d_in[5];
  const float* lnb  = (const float*)d_in[6];
  const float* W1   = (const float*)d_in[7];
  const float* b1   = (const float*)d_in[8];
  const float* W2   = (const float*)d_in[9];
  const float* b2   = (const float*)d_in[10];
  float* out = (float*)d_out;

  const int B = in_sizes[0] / 64;        // 131072
  const int grid = B / BROWS;            // 2048
  hipLaunchKernelGGL(tab_fused, dim3(grid), dim3(256), 0, stream,
                     xc, xcat, emb, Wc, bc, lng, lnb, W1, b1, W2, b2, out);
}